// Round 11
// baseline (16049.232 us; speedup 1.0000x reference)
//
#include <hip/hip_runtime.h>

#pragma clang fp contract(off)

#define BATCH 2
#define NPTS  16384
#define SS    4096
#define NSAMP 32
#define CIN   64
#define GPB   8          // FPS blocks per batch

// ---------------------------------------------------------------------------
// prep: transpose features (B,64,N) -> (B,N,64); pack W0 (64x67) -> (64x68, 0-pad)
// ---------------------------------------------------------------------------
__global__ __launch_bounds__(256) void prep_kernel(
    const float* __restrict__ feat, const float* __restrict__ W0,
    float* __restrict__ ftr, float* __restrict__ W0p)
{
    __shared__ float tl[64][65];
    const int t = threadIdx.x;
    const int blk = blockIdx.x;
    if (blk < BATCH * (NPTS / 64)) {
        const int b  = blk / (NPTS / 64);
        const int n0 = (blk % (NPTS / 64)) * 64;
        #pragma unroll
        for (int k = 0; k < 16; ++k) {
            int c = k * 4 + (t >> 6);
            int n = t & 63;
            tl[c][n] = feat[((size_t)b * CIN + c) * NPTS + n0 + n];
        }
        __syncthreads();
        #pragma unroll
        for (int k = 0; k < 16; ++k) {
            int n = k * 4 + (t >> 6);
            int c = t & 63;
            ftr[((size_t)b * NPTS + n0 + n) * CIN + c] = tl[c][n];
        }
    } else {
        for (int i = t; i < 64 * 68; i += 256) {
            int r = i / 68, c = i % 68;
            W0p[i] = (c < 67) ? W0[r * 67 + c] : 0.f;
        }
    }
}

// ---------------------------------------------------------------------------
// FPS v6: multi-CU. r10 closed the model: single-CU FPS is VALU-ISSUE-bound
// (98% active-CU VALUBusy); only more CUs help. 8 blocks/batch, 2048 pts each
// (2/thread in regs -- 8 VGPRs, resident at any RA budget). Cross-block
// combine = ONE round trip: each block release-stores a packed u64 key
//   (float_bits(bv) << 32) | (0xFFFFFFFF - idx)
// (bv>=0 -> bits monotone; max key == max val, tie -> min original index ==
// numpy argmax first-occurrence) into its zeroed slot, then polls all 8
// slots until non-zero and takes the max locally -- deterministic,
// atomic-order-free, bit-exact. Winner coords from read-only xyz (no
// coherence hazard). Exact FP: contract off, ((dx2+dy2)+dz2).
// ---------------------------------------------------------------------------
__global__ __launch_bounds__(1024) void fps_kernel(
    const float* __restrict__ xyz, float* __restrict__ newxyz,
    unsigned long long* __restrict__ slots)   // [BATCH][SS][GPB], pre-zeroed
{
    #pragma clang fp contract(off)
    const int blk = blockIdx.x;     // 0..BATCH*GPB-1
    const int b   = blk >> 3;       // batch
    const int g   = blk & (GPB - 1);
    const int t   = threadIdx.x;
    const float* xb = xyz + (size_t)b * NPTS * 3;
    unsigned long long* sb = slots + (size_t)b * SS * GPB;

    // two points per thread, coords + md in registers (8 VGPRs state)
    const int p0 = (g << 11) + (t << 1);
    const int p1 = p0 + 1;
    float x0 = xb[p0 * 3 + 0], y0 = xb[p0 * 3 + 1], z0 = xb[p0 * 3 + 2];
    float x1 = xb[p1 * 3 + 0], y1 = xb[p1 * 3 + 1], z1 = xb[p1 * 3 + 2];
    float md0 = 1e10f, md1 = 1e10f;

    __shared__ float2 s_w[16];   // per-wave (bv, bi-bits)
    __shared__ float  s_c[3];    // broadcast winner coords

    float lx = xb[0], ly = xb[1], lz = xb[2];
    if (g == 0 && t == 0) {
        float* o = newxyz + (size_t)b * SS * 3;
        o[0] = lx; o[1] = ly; o[2] = lz;
    }

    for (int s = 1; s < SS; ++s) {
        // ---- update both points (exact order, contract off)
        float dx0 = x0 - lx, dy0 = y0 - ly, dz0 = z0 - lz;
        float d0 = (dx0 * dx0 + dy0 * dy0) + dz0 * dz0;
        md0 = d0 < md0 ? d0 : md0;
        float dx1 = x1 - lx, dy1 = y1 - ly, dz1 = z1 - lz;
        float d1 = (dx1 * dx1 + dy1 * dy1) + dz1 * dz1;
        md1 = d1 < md1 ? d1 : md1;

        // thread best (tie -> p0, the smaller index)
        float bv = md1 > md0 ? md1 : md0;
        int   bi = md1 > md0 ? p1 : p0;

        // ---- wave butterfly argmax (shfl was never the bottleneck; min VALU)
        #pragma unroll
        for (int m = 1; m < 64; m <<= 1) {
            float ov = __shfl_xor(bv, m);
            int   oi = __shfl_xor(bi, m);
            bool tk = (ov > bv) || (ov == bv && oi < bi);
            if (tk) { bv = ov; bi = oi; }
        }
        if ((t & 63) == 0) s_w[t >> 6] = make_float2(bv, __int_as_float(bi));
        __syncthreads();

        // ---- wave 0 reduces the 16 wave-winners, lane 0 does global combine
        if (t < 64) {
            float2 rw = s_w[t & 15];
            float rv = rw.x;
            int   ri = __float_as_int(rw.y);
            #pragma unroll
            for (int m = 1; m < 16; m <<= 1) {
                float ov = __shfl_xor(rv, m);
                int   oi = __shfl_xor(ri, m);
                bool tk = (ov > rv) || (ov == rv && oi < ri);
                if (tk) { rv = ov; ri = oi; }
            }
            if (t == 0) {
                unsigned long long key =
                    ((unsigned long long)__float_as_uint(rv) << 32) |
                    (unsigned long long)(0xFFFFFFFFu - (unsigned)ri);
                __hip_atomic_store(&sb[(size_t)s * GPB + g], key,
                                   __ATOMIC_RELEASE, __HIP_MEMORY_SCOPE_AGENT);
                // poll all GPB slots until every block has published
                unsigned long long best;
                for (;;) {
                    best = 0ull;
                    bool all = true;
                    #pragma unroll
                    for (int j = 0; j < GPB; ++j) {
                        unsigned long long kk = __hip_atomic_load(
                            &sb[(size_t)s * GPB + j],
                            __ATOMIC_ACQUIRE, __HIP_MEMORY_SCOPE_AGENT);
                        all = all && (kk != 0ull);
                        best = kk > best ? kk : best;
                    }
                    if (all) break;
                }
                const int wi = (int)(0xFFFFFFFFu - (unsigned)best);
                float wx = xb[wi * 3 + 0];
                float wy = xb[wi * 3 + 1];
                float wz = xb[wi * 3 + 2];
                s_c[0] = wx; s_c[1] = wy; s_c[2] = wz;
                if (g == 0) {
                    float* o = newxyz + ((size_t)b * SS + s) * 3;
                    o[0] = wx; o[1] = wy; o[2] = wz;
                }
            }
        }
        __syncthreads();
        lx = s_c[0]; ly = s_c[1]; lz = s_c[2];
    }
}

// ---------------------------------------------------------------------------
// Ball query: one wave per query. First NSAMP valid indices in index order,
// pad with first valid, cnt flag. Exact FP compare semantics.
// ---------------------------------------------------------------------------
__global__ __launch_bounds__(256) void bq_kernel(
    const float* __restrict__ xyz, const float* __restrict__ newxyz,
    int* __restrict__ idxout, int* __restrict__ cntout)
{
    #pragma clang fp contract(off)
    const int lane = threadIdx.x & 63;
    const int q = blockIdx.x * 4 + (threadIdx.x >> 6);
    const int b = q >> 12;
    const float r2 = (float)(0.08 * 0.08);
    const float cx = newxyz[q * 3 + 0];
    const float cy = newxyz[q * 3 + 1];
    const float cz = newxyz[q * 3 + 2];
    const float* xb = xyz + (size_t)b * NPTS * 3;

    int found = 0;
    int idx0 = 0;
    for (int base = 0; base < NPTS; base += 64) {
        int p = base + lane;
        float dx = xb[p * 3 + 0] - cx;
        float dy = xb[p * 3 + 1] - cy;
        float dz = xb[p * 3 + 2] - cz;
        float d2 = (dx * dx + dy * dy) + dz * dz;   // contract(off)
        bool valid = d2 < r2;
        unsigned long long mask = __ballot(valid);
        if (mask) {
            if (found == 0) idx0 = base + (__ffsll(mask) - 1);
            int rank = found + __popcll(mask & ((1ull << lane) - 1ull));
            if (valid && rank < NSAMP) idxout[(size_t)q * NSAMP + rank] = p;
            found += (int)__popcll(mask);
            if (found >= NSAMP) break;
        }
    }
    if (found < NSAMP) {
        int pad = (found > 0) ? idx0 : 0;
        if (found + lane < NSAMP) idxout[(size_t)q * NSAMP + found + lane] = pad;
    }
    if (lane == 0) cntout[q] = found;
}

// ---------------------------------------------------------------------------
// Fused gather + 3-layer 1x1-conv MLP + masked max-pool.
// One wave per group; X/Y tiles in LDS (row stride 36 floats, conflict-free
// float4 access); weights streamed from global (L1-resident); explicit fmaf.
// ---------------------------------------------------------------------------
__global__ __launch_bounds__(128) void mlp_kernel(
    const float* __restrict__ xyz, const float* __restrict__ newxyz,
    const float* __restrict__ ftr, const int* __restrict__ idxbuf,
    const int* __restrict__ cntbuf, const float* __restrict__ W0p,
    const float* __restrict__ b0, const float* __restrict__ W1,
    const float* __restrict__ b1, const float* __restrict__ W2,
    const float* __restrict__ b2, float* __restrict__ outfeat)
{
    __shared__ float sX[2][68 * 36];
    __shared__ float sY[2][64 * 36];
    const int w    = threadIdx.x >> 6;
    const int lane = threadIdx.x & 63;
    const int g = blockIdx.x * 2 + w;
    const int b = g >> 12;
    const int s = g & (SS - 1);
    float* X = sX[w];
    float* Y = sY[w];

    const int n = lane & 31, h = lane >> 5;
    const int pidx = idxbuf[(size_t)g * NSAMP + n];
    const float cx = newxyz[g * 3 + 0];
    const float cy = newxyz[g * 3 + 1];
    const float cz = newxyz[g * 3 + 2];

    if (h == 0) {
        const float* p = xyz + ((size_t)b * NPTS + pidx) * 3;
        X[0 * 36 + n] = p[0] - cx;
        X[1 * 36 + n] = p[1] - cy;
        X[2 * 36 + n] = p[2] - cz;
        X[67 * 36 + n] = 0.f;
    }
    {
        const float4* f4 = (const float4*)(ftr + ((size_t)b * NPTS + pidx) * CIN + h * 32);
        #pragma unroll
        for (int j = 0; j < 8; ++j) {
            float4 v = f4[j];
            int c = 3 + h * 32 + j * 4;
            X[(c + 0) * 36 + n] = v.x;
            X[(c + 1) * 36 + n] = v.y;
            X[(c + 2) * 36 + n] = v.z;
            X[(c + 3) * 36 + n] = v.w;
        }
    }
    __syncthreads();

    const int og = lane >> 3, ng = lane & 7;

    // ---- Layer 0: 67(->68) -> 64
    float acc0[8][4];
    #pragma unroll
    for (int j = 0; j < 8; ++j)
        #pragma unroll
        for (int nn = 0; nn < 4; ++nn) acc0[j][nn] = 0.f;
    for (int cb = 0; cb < 17; ++cb) {
        const int c = cb * 4;
        float4 xr0 = *(const float4*)&X[(c + 0) * 36 + ng * 4];
        float4 xr1 = *(const float4*)&X[(c + 1) * 36 + ng * 4];
        float4 xr2 = *(const float4*)&X[(c + 2) * 36 + ng * 4];
        float4 xr3 = *(const float4*)&X[(c + 3) * 36 + ng * 4];
        #pragma unroll
        for (int j = 0; j < 8; ++j) {
            float4 wv = *(const float4*)&W0p[(size_t)(og * 8 + j) * 68 + c];
            acc0[j][0] = fmaf(wv.x, xr0.x, acc0[j][0]);
            acc0[j][1] = fmaf(wv.x, xr0.y, acc0[j][1]);
            acc0[j][2] = fmaf(wv.x, xr0.z, acc0[j][2]);
            acc0[j][3] = fmaf(wv.x, xr0.w, acc0[j][3]);
            acc0[j][0] = fmaf(wv.y, xr1.x, acc0[j][0]);
            acc0[j][1] = fmaf(wv.y, xr1.y, acc0[j][1]);
            acc0[j][2] = fmaf(wv.y, xr1.z, acc0[j][2]);
            acc0[j][3] = fmaf(wv.y, xr1.w, acc0[j][3]);
            acc0[j][0] = fmaf(wv.z, xr2.x, acc0[j][0]);
            acc0[j][1] = fmaf(wv.z, xr2.y, acc0[j][1]);
            acc0[j][2] = fmaf(wv.z, xr2.z, acc0[j][2]);
            acc0[j][3] = fmaf(wv.z, xr2.w, acc0[j][3]);
            acc0[j][0] = fmaf(wv.w, xr3.x, acc0[j][0]);
            acc0[j][1] = fmaf(wv.w, xr3.y, acc0[j][1]);
            acc0[j][2] = fmaf(wv.w, xr3.z, acc0[j][2]);
            acc0[j][3] = fmaf(wv.w, xr3.w, acc0[j][3]);
        }
    }
    #pragma unroll
    for (int j = 0; j < 8; ++j) {
        const float bv = b0[og * 8 + j];
        float4 yv;
        yv.x = fmaxf(acc0[j][0] + bv, 0.f);
        yv.y = fmaxf(acc0[j][1] + bv, 0.f);
        yv.z = fmaxf(acc0[j][2] + bv, 0.f);
        yv.w = fmaxf(acc0[j][3] + bv, 0.f);
        *(float4*)&Y[(og * 8 + j) * 36 + ng * 4] = yv;
    }
    __syncthreads();

    // ---- Layer 1: 64 -> 64  (Y -> X rows 0..63)
    float acc1[8][4];
    #pragma unroll
    for (int j = 0; j < 8; ++j)
        #pragma unroll
        for (int nn = 0; nn < 4; ++nn) acc1[j][nn] = 0.f;
    for (int cb = 0; cb < 16; ++cb) {
        const int c = cb * 4;
        float4 xr0 = *(const float4*)&Y[(c + 0) * 36 + ng * 4];
        float4 xr1 = *(const float4*)&Y[(c + 1) * 36 + ng * 4];
        float4 xr2 = *(const float4*)&Y[(c + 2) * 36 + ng * 4];
        float4 xr3 = *(const float4*)&Y[(c + 3) * 36 + ng * 4];
        #pragma unroll
        for (int j = 0; j < 8; ++j) {
            float4 wv = *(const float4*)&W1[(size_t)(og * 8 + j) * 64 + c];
            acc1[j][0] = fmaf(wv.x, xr0.x, acc1[j][0]);
            acc1[j][1] = fmaf(wv.x, xr0.y, acc1[j][1]);
            acc1[j][2] = fmaf(wv.x, xr0.z, acc1[j][2]);
            acc1[j][3] = fmaf(wv.x, xr0.w, acc1[j][3]);
            acc1[j][0] = fmaf(wv.y, xr1.x, acc1[j][0]);
            acc1[j][1] = fmaf(wv.y, xr1.y, acc1[j][1]);
            acc1[j][2] = fmaf(wv.y, xr1.z, acc1[j][2]);
            acc1[j][3] = fmaf(wv.y, xr1.w, acc1[j][3]);
            acc1[j][0] = fmaf(wv.z, xr2.x, acc1[j][0]);
            acc1[j][1] = fmaf(wv.z, xr2.y, acc1[j][1]);
            acc1[j][2] = fmaf(wv.z, xr2.z, acc1[j][2]);
            acc1[j][3] = fmaf(wv.z, xr2.w, acc1[j][3]);
            acc1[j][0] = fmaf(wv.w, xr3.x, acc1[j][0]);
            acc1[j][1] = fmaf(wv.w, xr3.y, acc1[j][1]);
            acc1[j][2] = fmaf(wv.w, xr3.z, acc1[j][2]);
            acc1[j][3] = fmaf(wv.w, xr3.w, acc1[j][3]);
        }
    }
    __syncthreads();   // X rows are about to be overwritten; Y reads done
    #pragma unroll
    for (int j = 0; j < 8; ++j) {
        const float bv = b1[og * 8 + j];
        float4 yv;
        yv.x = fmaxf(acc1[j][0] + bv, 0.f);
        yv.y = fmaxf(acc1[j][1] + bv, 0.f);
        yv.z = fmaxf(acc1[j][2] + bv, 0.f);
        yv.w = fmaxf(acc1[j][3] + bv, 0.f);
        *(float4*)&X[(og * 8 + j) * 36 + ng * 4] = yv;
    }
    __syncthreads();

    // ---- Layer 2: 64 -> 128 (X rows 0..63 -> registers) + masked max-pool
    float acc2[16][4];
    #pragma unroll
    for (int j = 0; j < 16; ++j)
        #pragma unroll
        for (int nn = 0; nn < 4; ++nn) acc2[j][nn] = 0.f;
    for (int cb = 0; cb < 16; ++cb) {
        const int c = cb * 4;
        float4 xr0 = *(const float4*)&X[(c + 0) * 36 + ng * 4];
        float4 xr1 = *(const float4*)&X[(c + 1) * 36 + ng * 4];
        float4 xr2 = *(const float4*)&X[(c + 2) * 36 + ng * 4];
        float4 xr3 = *(const float4*)&X[(c + 3) * 36 + ng * 4];
        #pragma unroll
        for (int j = 0; j < 16; ++j) {
            float4 wv = *(const float4*)&W2[(size_t)(og * 16 + j) * 64 + c];
            acc2[j][0] = fmaf(wv.x, xr0.x, acc2[j][0]);
            acc2[j][1] = fmaf(wv.x, xr0.y, acc2[j][1]);
            acc2[j][2] = fmaf(wv.x, xr0.z, acc2[j][2]);
            acc2[j][3] = fmaf(wv.x, xr0.w, acc2[j][3]);
            acc2[j][0] = fmaf(wv.y, xr1.x, acc2[j][0]);
            acc2[j][1] = fmaf(wv.y, xr1.y, acc2[j][1]);
            acc2[j][2] = fmaf(wv.y, xr1.z, acc2[j][2]);
            acc2[j][3] = fmaf(wv.y, xr1.w, acc2[j][3]);
            acc2[j][0] = fmaf(wv.z, xr2.x, acc2[j][0]);
            acc2[j][1] = fmaf(wv.z, xr2.y, acc2[j][1]);
            acc2[j][2] = fmaf(wv.z, xr2.z, acc2[j][2]);
            acc2[j][3] = fmaf(wv.z, xr2.w, acc2[j][3]);
            acc2[j][0] = fmaf(wv.w, xr3.x, acc2[j][0]);
            acc2[j][1] = fmaf(wv.w, xr3.y, acc2[j][1]);
            acc2[j][2] = fmaf(wv.w, xr3.z, acc2[j][2]);
            acc2[j][3] = fmaf(wv.w, xr3.w, acc2[j][3]);
        }
    }

    const int cnt = cntbuf[g];
    const float msk = (cnt > 0) ? 1.f : 0.f;
    float* ob = outfeat + ((size_t)b * 128) * SS + s;
    float mj[16];
    #pragma unroll
    for (int j = 0; j < 16; ++j) {
        const float bv = b2[og * 16 + j];
        float v0 = fmaxf(acc2[j][0] + bv, acc2[j][1] + bv);
        float v1 = fmaxf(acc2[j][2] + bv, acc2[j][3] + bv);
        float v = fmaxf(fmaxf(v0, v1), 0.f);
        v = fmaxf(v, __shfl_xor(v, 1));
        v = fmaxf(v, __shfl_xor(v, 2));
        v = fmaxf(v, __shfl_xor(v, 4));
        mj[j] = v * msk;
    }
    if (ng == 0) {
        #pragma unroll
        for (int j = 0; j < 16; ++j)
            ob[(size_t)(og * 16 + j) * SS] = mj[j];
    }
}

// ---------------------------------------------------------------------------
extern "C" void kernel_launch(void* const* d_in, const int* in_sizes, int n_in,
                              void* d_out, int out_size, void* d_ws, size_t ws_size,
                              hipStream_t stream)
{
    (void)in_sizes; (void)n_in; (void)out_size; (void)ws_size;
    const float* xyz  = (const float*)d_in[0];
    const float* feat = (const float*)d_in[1];
    const float* W0 = (const float*)d_in[2];
    const float* b0 = (const float*)d_in[3];
    const float* W1 = (const float*)d_in[4];
    const float* b1 = (const float*)d_in[5];
    const float* W2 = (const float*)d_in[6];
    const float* b2 = (const float*)d_in[7];

    float* out     = (float*)d_out;
    float* newxyz  = out;                          // (B,S,3)
    float* outfeat = out + (size_t)BATCH * SS * 3; // (B,128,S)

    char* ws = (char*)d_ws;
    float* ftr = (float*)ws;                                   // B*N*64 f32 (8 MB)
    size_t off = (size_t)BATCH * NPTS * CIN * sizeof(float);
    int* idxbuf = (int*)(ws + off); off += (size_t)BATCH * SS * NSAMP * sizeof(int);
    int* cntbuf = (int*)(ws + off); off += (size_t)BATCH * SS * sizeof(int);
    float* W0p  = (float*)(ws + off); off += 64 * 68 * sizeof(float);
    unsigned long long* slots = (unsigned long long*)(ws + off);
    const size_t slots_bytes = (size_t)BATCH * SS * GPB * sizeof(unsigned long long);

    hipMemsetAsync(slots, 0, slots_bytes, stream);   // fresh handshake slots each call
    prep_kernel<<<dim3(BATCH * (NPTS / 64) + 1), dim3(256), 0, stream>>>(feat, W0, ftr, W0p);
    fps_kernel<<<dim3(BATCH * GPB), dim3(1024), 0, stream>>>(xyz, newxyz, slots);
    bq_kernel<<<dim3(BATCH * SS / 4), dim3(256), 0, stream>>>(xyz, newxyz, idxbuf, cntbuf);
    mlp_kernel<<<dim3(BATCH * SS / 2), dim3(128), 0, stream>>>(
        xyz, newxyz, ftr, idxbuf, cntbuf, W0p, b0, W1, b1, W2, b2, outfeat);
}

// Round 12
// 9847.725 us; speedup vs baseline: 1.6297x; 1.6297x over previous
//
#include <hip/hip_runtime.h>

#pragma clang fp contract(off)

#define BATCH 2
#define NPTS  16384
#define SS    4096
#define NSAMP 32
#define CIN   64

typedef float v2f __attribute__((ext_vector_type(2)));

// ---------------------------------------------------------------------------
// prep: transpose features (B,64,N) -> (B,N,64); pack W0 (64x67) -> (64x68, 0-pad)
// ---------------------------------------------------------------------------
__global__ __launch_bounds__(256) void prep_kernel(
    const float* __restrict__ feat, const float* __restrict__ W0,
    float* __restrict__ ftr, float* __restrict__ W0p)
{
    __shared__ float tl[64][65];
    const int t = threadIdx.x;
    const int blk = blockIdx.x;
    if (blk < BATCH * (NPTS / 64)) {
        const int b  = blk / (NPTS / 64);
        const int n0 = (blk % (NPTS / 64)) * 64;
        #pragma unroll
        for (int k = 0; k < 16; ++k) {
            int c = k * 4 + (t >> 6);
            int n = t & 63;
            tl[c][n] = feat[((size_t)b * CIN + c) * NPTS + n0 + n];
        }
        __syncthreads();
        #pragma unroll
        for (int k = 0; k < 16; ++k) {
            int n = k * 4 + (t >> 6);
            int c = t & 63;
            ftr[((size_t)b * NPTS + n0 + n) * CIN + c] = tl[c][n];
        }
    } else {
        for (int i = t; i < 64 * 68; i += 256) {
            int r = i / 68, c = i % 68;
            W0p[i] = (c < 67) ? W0[r * 67 + c] : 0.f;
        }
    }
}

// ---------------------------------------------------------------------------
// FPS v7: r9 skeleton + PACKED-FP32 update loop (v_pk_add/mul_f32, VOP3P --
// hipcc never emits these from scalar code; inline asm). LDS holds x-pairs
// and y-pairs {v(p), v(p+8192)}; z-pairs in registers. 2 points cost
// 8 packed ops + 2 v_min vs ~22 scalar ops. Bit-exact: pk_add(x, -l) == x-l
// (pre-negated center), per-half order ((dx2+dy2)+dz2) preserved, fminf ==
// select on our no-NaN domain. Index map (k<<10)+t unchanged -> argmax/scan/
// butterfly identical to r9 (passed, absmax 0).
// ---------------------------------------------------------------------------
__global__ __launch_bounds__(1024) void fps_kernel(
    const float* __restrict__ xyz, float* __restrict__ newxyz)
{
    #pragma clang fp contract(off)
    const int b = blockIdx.x;
    const int t = threadIdx.x;
    const float* xb = xyz + (size_t)b * NPTS * 3;

    __shared__ v2f sx2[NPTS / 2];    // 64 KB: {x_p, x_{p+8192}}
    __shared__ v2f sy2[NPTS / 2];    // 64 KB: {y_p, y_{p+8192}}
    __shared__ float2 s_w[2][16];    // per-wave (bv, bi-bits), double-buffered

    v2f   zp[8];
    float md[16];
    #pragma unroll
    for (int k = 0; k < 8; ++k) {
        int p = (k << 10) + t;
        int q = p + 8192;
        float xa = xb[p * 3 + 0], ya = xb[p * 3 + 1], za = xb[p * 3 + 2];
        float xc = xb[q * 3 + 0], yc = xb[q * 3 + 1], zc = xb[q * 3 + 2];
        v2f vx; vx.x = xa; vx.y = xc;
        v2f vy; vy.x = ya; vy.y = yc;
        v2f vz; vz.x = za; vz.y = zc;
        sx2[p] = vx;
        sy2[p] = vy;
        zp[k] = vz;
        md[k] = 1e10f;
        md[k + 8] = 1e10f;
    }
    __syncthreads();

    const v2f* px = sx2 + t;    // k-pair offsets k*8192 B (imm, <64 KB)
    const v2f* py = sy2 + t;

    float lx = xb[0], ly = xb[1], lz = xb[2];
    if (t == 0) {
        float* o = newxyz + (size_t)b * SS * 3;
        o[0] = lx; o[1] = ly; o[2] = lz;
    }

    for (int s = 1; s < SS; ++s) {
        // pre-negated broadcast pairs (x + (-l) == x - l, bit-exact)
        const float nlx = -lx, nly = -ly, nlz = -lz;
        v2f nlx2; nlx2.x = nlx; nlx2.y = nlx;
        v2f nly2; nly2.x = nly; nly2.y = nly;
        v2f nlz2; nlz2.x = nlz; nlz2.y = nlz;

        // ---- packed min-update: 2 points per iteration
        #pragma unroll
        for (int k = 0; k < 8; ++k) {
            v2f xp = px[k << 10];
            v2f yp = py[k << 10];
            v2f dx, dy, dz, xx, yy, ss, zz, dd;
            asm("v_pk_add_f32 %0, %1, %2" : "=v"(dx) : "v"(xp),    "v"(nlx2));
            asm("v_pk_add_f32 %0, %1, %2" : "=v"(dy) : "v"(yp),    "v"(nly2));
            asm("v_pk_add_f32 %0, %1, %2" : "=v"(dz) : "v"(zp[k]), "v"(nlz2));
            asm("v_pk_mul_f32 %0, %1, %1" : "=v"(xx) : "v"(dx));
            asm("v_pk_mul_f32 %0, %1, %1" : "=v"(yy) : "v"(dy));
            asm("v_pk_add_f32 %0, %1, %2" : "=v"(ss) : "v"(xx), "v"(yy));
            asm("v_pk_mul_f32 %0, %1, %1" : "=v"(zz) : "v"(dz));
            asm("v_pk_add_f32 %0, %1, %2" : "=v"(dd) : "v"(ss), "v"(zz));
            md[k]     = fminf(dd.x, md[k]);      // ((dx2+dy2)+dz2) order kept
            md[k + 8] = fminf(dd.y, md[k + 8]);
        }

        // ---- bv = max over md (exact; max associative), v_max3-friendly tree
        float t0 = fmaxf(fmaxf(md[0],  md[1]),  md[2]);
        float t1 = fmaxf(fmaxf(md[3],  md[4]),  md[5]);
        float t2 = fmaxf(fmaxf(md[6],  md[7]),  md[8]);
        float t3 = fmaxf(fmaxf(md[9],  md[10]), md[11]);
        float t4 = fmaxf(fmaxf(md[12], md[13]), md[14]);
        float u0 = fmaxf(fmaxf(t0, t1), t2);
        float u1 = fmaxf(fmaxf(t3, t4), md[15]);
        float bv = fmaxf(u0, u1);

        // ---- bk = smallest k with md[k]==bv (index monotone in k)
        int bk = 0;
        #pragma unroll
        for (int k = 15; k >= 0; --k)
            if (md[k] == bv) bk = k;
        int bi = (bk << 10) + t;

        // ---- wave butterfly argmax, payload (bv, bi)
        #pragma unroll
        for (int m = 1; m < 64; m <<= 1) {
            float ov = __shfl_xor(bv, m);
            int   oi = __shfl_xor(bi, m);
            bool take = (ov > bv) || (ov == bv && oi < bi);
            if (take) { bv = ov; bi = oi; }
        }

        const int pb = s & 1;
        if ((t & 63) == 0)
            s_w[pb][t >> 6] = make_float2(bv, __int_as_float(bi));
        __syncthreads();

        // ---- every wave redundantly reduces the 16 wave-winners
        float2 rw = s_w[pb][t & 15];
        float rv = rw.x;
        int   ri = __float_as_int(rw.y);
        #pragma unroll
        for (int m = 1; m < 16; m <<= 1) {
            float ov = __shfl_xor(rv, m);
            int   oi = __shfl_xor(ri, m);
            bool take = (ov > rv) || (ov == rv && oi < ri);
            if (take) { rv = ov; ri = oi; }
        }

        // winner coords from global (uniform address, L1/L2-resident)
        const int wi = __builtin_amdgcn_readfirstlane(ri);
        lx = xb[wi * 3 + 0];
        ly = xb[wi * 3 + 1];
        lz = xb[wi * 3 + 2];
        if (t == 0) {
            float* o = newxyz + ((size_t)b * SS + s) * 3;
            o[0] = lx; o[1] = ly; o[2] = lz;
        }
    }
}

// ---------------------------------------------------------------------------
// Ball query: one wave per query. First NSAMP valid indices in index order,
// pad with first valid, cnt flag. Exact FP compare semantics.
// ---------------------------------------------------------------------------
__global__ __launch_bounds__(256) void bq_kernel(
    const float* __restrict__ xyz, const float* __restrict__ newxyz,
    int* __restrict__ idxout, int* __restrict__ cntout)
{
    #pragma clang fp contract(off)
    const int lane = threadIdx.x & 63;
    const int q = blockIdx.x * 4 + (threadIdx.x >> 6);
    const int b = q >> 12;
    const float r2 = (float)(0.08 * 0.08);
    const float cx = newxyz[q * 3 + 0];
    const float cy = newxyz[q * 3 + 1];
    const float cz = newxyz[q * 3 + 2];
    const float* xb = xyz + (size_t)b * NPTS * 3;

    int found = 0;
    int idx0 = 0;
    for (int base = 0; base < NPTS; base += 64) {
        int p = base + lane;
        float dx = xb[p * 3 + 0] - cx;
        float dy = xb[p * 3 + 1] - cy;
        float dz = xb[p * 3 + 2] - cz;
        float d2 = (dx * dx + dy * dy) + dz * dz;   // contract(off)
        bool valid = d2 < r2;
        unsigned long long mask = __ballot(valid);
        if (mask) {
            if (found == 0) idx0 = base + (__ffsll(mask) - 1);
            int rank = found + __popcll(mask & ((1ull << lane) - 1ull));
            if (valid && rank < NSAMP) idxout[(size_t)q * NSAMP + rank] = p;
            found += (int)__popcll(mask);
            if (found >= NSAMP) break;
        }
    }
    if (found < NSAMP) {
        int pad = (found > 0) ? idx0 : 0;
        if (found + lane < NSAMP) idxout[(size_t)q * NSAMP + found + lane] = pad;
    }
    if (lane == 0) cntout[q] = found;
}

// ---------------------------------------------------------------------------
// Fused gather + 3-layer 1x1-conv MLP + masked max-pool.
// One wave per group; X/Y tiles in LDS (row stride 36 floats, conflict-free
// float4 access); weights streamed from global (L1-resident); explicit fmaf.
// ---------------------------------------------------------------------------
__global__ __launch_bounds__(128) void mlp_kernel(
    const float* __restrict__ xyz, const float* __restrict__ newxyz,
    const float* __restrict__ ftr, const int* __restrict__ idxbuf,
    const int* __restrict__ cntbuf, const float* __restrict__ W0p,
    const float* __restrict__ b0, const float* __restrict__ W1,
    const float* __restrict__ b1, const float* __restrict__ W2,
    const float* __restrict__ b2, float* __restrict__ outfeat)
{
    __shared__ float sX[2][68 * 36];
    __shared__ float sY[2][64 * 36];
    const int w    = threadIdx.x >> 6;
    const int lane = threadIdx.x & 63;
    const int g = blockIdx.x * 2 + w;
    const int b = g >> 12;
    const int s = g & (SS - 1);
    float* X = sX[w];
    float* Y = sY[w];

    const int n = lane & 31, h = lane >> 5;
    const int pidx = idxbuf[(size_t)g * NSAMP + n];
    const float cx = newxyz[g * 3 + 0];
    const float cy = newxyz[g * 3 + 1];
    const float cz = newxyz[g * 3 + 2];

    if (h == 0) {
        const float* p = xyz + ((size_t)b * NPTS + pidx) * 3;
        X[0 * 36 + n] = p[0] - cx;
        X[1 * 36 + n] = p[1] - cy;
        X[2 * 36 + n] = p[2] - cz;
        X[67 * 36 + n] = 0.f;
    }
    {
        const float4* f4 = (const float4*)(ftr + ((size_t)b * NPTS + pidx) * CIN + h * 32);
        #pragma unroll
        for (int j = 0; j < 8; ++j) {
            float4 v = f4[j];
            int c = 3 + h * 32 + j * 4;
            X[(c + 0) * 36 + n] = v.x;
            X[(c + 1) * 36 + n] = v.y;
            X[(c + 2) * 36 + n] = v.z;
            X[(c + 3) * 36 + n] = v.w;
        }
    }
    __syncthreads();

    const int og = lane >> 3, ng = lane & 7;

    // ---- Layer 0: 67(->68) -> 64
    float acc0[8][4];
    #pragma unroll
    for (int j = 0; j < 8; ++j)
        #pragma unroll
        for (int nn = 0; nn < 4; ++nn) acc0[j][nn] = 0.f;
    for (int cb = 0; cb < 17; ++cb) {
        const int c = cb * 4;
        float4 xr0 = *(const float4*)&X[(c + 0) * 36 + ng * 4];
        float4 xr1 = *(const float4*)&X[(c + 1) * 36 + ng * 4];
        float4 xr2 = *(const float4*)&X[(c + 2) * 36 + ng * 4];
        float4 xr3 = *(const float4*)&X[(c + 3) * 36 + ng * 4];
        #pragma unroll
        for (int j = 0; j < 8; ++j) {
            float4 wv = *(const float4*)&W0p[(size_t)(og * 8 + j) * 68 + c];
            acc0[j][0] = fmaf(wv.x, xr0.x, acc0[j][0]);
            acc0[j][1] = fmaf(wv.x, xr0.y, acc0[j][1]);
            acc0[j][2] = fmaf(wv.x, xr0.z, acc0[j][2]);
            acc0[j][3] = fmaf(wv.x, xr0.w, acc0[j][3]);
            acc0[j][0] = fmaf(wv.y, xr1.x, acc0[j][0]);
            acc0[j][1] = fmaf(wv.y, xr1.y, acc0[j][1]);
            acc0[j][2] = fmaf(wv.y, xr1.z, acc0[j][2]);
            acc0[j][3] = fmaf(wv.y, xr1.w, acc0[j][3]);
            acc0[j][0] = fmaf(wv.z, xr2.x, acc0[j][0]);
            acc0[j][1] = fmaf(wv.z, xr2.y, acc0[j][1]);
            acc0[j][2] = fmaf(wv.z, xr2.z, acc0[j][2]);
            acc0[j][3] = fmaf(wv.z, xr2.w, acc0[j][3]);
            acc0[j][0] = fmaf(wv.w, xr3.x, acc0[j][0]);
            acc0[j][1] = fmaf(wv.w, xr3.y, acc0[j][1]);
            acc0[j][2] = fmaf(wv.w, xr3.z, acc0[j][2]);
            acc0[j][3] = fmaf(wv.w, xr3.w, acc0[j][3]);
        }
    }
    #pragma unroll
    for (int j = 0; j < 8; ++j) {
        const float bv = b0[og * 8 + j];
        float4 yv;
        yv.x = fmaxf(acc0[j][0] + bv, 0.f);
        yv.y = fmaxf(acc0[j][1] + bv, 0.f);
        yv.z = fmaxf(acc0[j][2] + bv, 0.f);
        yv.w = fmaxf(acc0[j][3] + bv, 0.f);
        *(float4*)&Y[(og * 8 + j) * 36 + ng * 4] = yv;
    }
    __syncthreads();

    // ---- Layer 1: 64 -> 64  (Y -> X rows 0..63)
    float acc1[8][4];
    #pragma unroll
    for (int j = 0; j < 8; ++j)
        #pragma unroll
        for (int nn = 0; nn < 4; ++nn) acc1[j][nn] = 0.f;
    for (int cb = 0; cb < 16; ++cb) {
        const int c = cb * 4;
        float4 xr0 = *(const float4*)&Y[(c + 0) * 36 + ng * 4];
        float4 xr1 = *(const float4*)&Y[(c + 1) * 36 + ng * 4];
        float4 xr2 = *(const float4*)&Y[(c + 2) * 36 + ng * 4];
        float4 xr3 = *(const float4*)&Y[(c + 3) * 36 + ng * 4];
        #pragma unroll
        for (int j = 0; j < 8; ++j) {
            float4 wv = *(const float4*)&W1[(size_t)(og * 8 + j) * 64 + c];
            acc1[j][0] = fmaf(wv.x, xr0.x, acc1[j][0]);
            acc1[j][1] = fmaf(wv.x, xr0.y, acc1[j][1]);
            acc1[j][2] = fmaf(wv.x, xr0.z, acc1[j][2]);
            acc1[j][3] = fmaf(wv.x, xr0.w, acc1[j][3]);
            acc1[j][0] = fmaf(wv.y, xr1.x, acc1[j][0]);
            acc1[j][1] = fmaf(wv.y, xr1.y, acc1[j][1]);
            acc1[j][2] = fmaf(wv.y, xr1.z, acc1[j][2]);
            acc1[j][3] = fmaf(wv.y, xr1.w, acc1[j][3]);
            acc1[j][0] = fmaf(wv.z, xr2.x, acc1[j][0]);
            acc1[j][1] = fmaf(wv.z, xr2.y, acc1[j][1]);
            acc1[j][2] = fmaf(wv.z, xr2.z, acc1[j][2]);
            acc1[j][3] = fmaf(wv.z, xr2.w, acc1[j][3]);
            acc1[j][0] = fmaf(wv.w, xr3.x, acc1[j][0]);
            acc1[j][1] = fmaf(wv.w, xr3.y, acc1[j][1]);
            acc1[j][2] = fmaf(wv.w, xr3.z, acc1[j][2]);
            acc1[j][3] = fmaf(wv.w, xr3.w, acc1[j][3]);
        }
    }
    __syncthreads();   // X rows are about to be overwritten; Y reads done
    #pragma unroll
    for (int j = 0; j < 8; ++j) {
        const float bv = b1[og * 8 + j];
        float4 yv;
        yv.x = fmaxf(acc1[j][0] + bv, 0.f);
        yv.y = fmaxf(acc1[j][1] + bv, 0.f);
        yv.z = fmaxf(acc1[j][2] + bv, 0.f);
        yv.w = fmaxf(acc1[j][3] + bv, 0.f);
        *(float4*)&X[(og * 8 + j) * 36 + ng * 4] = yv;
    }
    __syncthreads();

    // ---- Layer 2: 64 -> 128 (X rows 0..63 -> registers) + masked max-pool
    float acc2[16][4];
    #pragma unroll
    for (int j = 0; j < 16; ++j)
        #pragma unroll
        for (int nn = 0; nn < 4; ++nn) acc2[j][nn] = 0.f;
    for (int cb = 0; cb < 16; ++cb) {
        const int c = cb * 4;
        float4 xr0 = *(const float4*)&X[(c + 0) * 36 + ng * 4];
        float4 xr1 = *(const float4*)&X[(c + 1) * 36 + ng * 4];
        float4 xr2 = *(const float4*)&X[(c + 2) * 36 + ng * 4];
        float4 xr3 = *(const float4*)&X[(c + 3) * 36 + ng * 4];
        #pragma unroll
        for (int j = 0; j < 16; ++j) {
            float4 wv = *(const float4*)&W2[(size_t)(og * 16 + j) * 64 + c];
            acc2[j][0] = fmaf(wv.x, xr0.x, acc2[j][0]);
            acc2[j][1] = fmaf(wv.x, xr0.y, acc2[j][1]);
            acc2[j][2] = fmaf(wv.x, xr0.z, acc2[j][2]);
            acc2[j][3] = fmaf(wv.x, xr0.w, acc2[j][3]);
            acc2[j][0] = fmaf(wv.y, xr1.x, acc2[j][0]);
            acc2[j][1] = fmaf(wv.y, xr1.y, acc2[j][1]);
            acc2[j][2] = fmaf(wv.y, xr1.z, acc2[j][2]);
            acc2[j][3] = fmaf(wv.y, xr1.w, acc2[j][3]);
            acc2[j][0] = fmaf(wv.z, xr2.x, acc2[j][0]);
            acc2[j][1] = fmaf(wv.z, xr2.y, acc2[j][1]);
            acc2[j][2] = fmaf(wv.z, xr2.z, acc2[j][2]);
            acc2[j][3] = fmaf(wv.z, xr2.w, acc2[j][3]);
            acc2[j][0] = fmaf(wv.w, xr3.x, acc2[j][0]);
            acc2[j][1] = fmaf(wv.w, xr3.y, acc2[j][1]);
            acc2[j][2] = fmaf(wv.w, xr3.z, acc2[j][2]);
            acc2[j][3] = fmaf(wv.w, xr3.w, acc2[j][3]);
        }
    }

    const int cnt = cntbuf[g];
    const float msk = (cnt > 0) ? 1.f : 0.f;
    float* ob = outfeat + ((size_t)b * 128) * SS + s;
    float mj[16];
    #pragma unroll
    for (int j = 0; j < 16; ++j) {
        const float bv = b2[og * 16 + j];
        float v0 = fmaxf(acc2[j][0] + bv, acc2[j][1] + bv);
        float v1 = fmaxf(acc2[j][2] + bv, acc2[j][3] + bv);
        float v = fmaxf(fmaxf(v0, v1), 0.f);
        v = fmaxf(v, __shfl_xor(v, 1));
        v = fmaxf(v, __shfl_xor(v, 2));
        v = fmaxf(v, __shfl_xor(v, 4));
        mj[j] = v * msk;
    }
    if (ng == 0) {
        #pragma unroll
        for (int j = 0; j < 16; ++j)
            ob[(size_t)(og * 16 + j) * SS] = mj[j];
    }
}

// ---------------------------------------------------------------------------
extern "C" void kernel_launch(void* const* d_in, const int* in_sizes, int n_in,
                              void* d_out, int out_size, void* d_ws, size_t ws_size,
                              hipStream_t stream)
{
    (void)in_sizes; (void)n_in; (void)out_size; (void)ws_size;
    const float* xyz  = (const float*)d_in[0];
    const float* feat = (const float*)d_in[1];
    const float* W0 = (const float*)d_in[2];
    const float* b0 = (const float*)d_in[3];
    const float* W1 = (const float*)d_in[4];
    const float* b1 = (const float*)d_in[5];
    const float* W2 = (const float*)d_in[6];
    const float* b2 = (const float*)d_in[7];

    float* out     = (float*)d_out;
    float* newxyz  = out;                          // (B,S,3)
    float* outfeat = out + (size_t)BATCH * SS * 3; // (B,128,S)

    char* ws = (char*)d_ws;
    float* ftr = (float*)ws;                                   // B*N*64 f32 (8 MB)
    size_t off = (size_t)BATCH * NPTS * CIN * sizeof(float);
    int* idxbuf = (int*)(ws + off); off += (size_t)BATCH * SS * NSAMP * sizeof(int);
    int* cntbuf = (int*)(ws + off); off += (size_t)BATCH * SS * sizeof(int);
    float* W0p  = (float*)(ws + off);

    prep_kernel<<<dim3(BATCH * (NPTS / 64) + 1), dim3(256), 0, stream>>>(feat, W0, ftr, W0p);
    fps_kernel<<<dim3(BATCH), dim3(1024), 0, stream>>>(xyz, newxyz);
    bq_kernel<<<dim3(BATCH * SS / 4), dim3(256), 0, stream>>>(xyz, newxyz, idxbuf, cntbuf);
    mlp_kernel<<<dim3(BATCH * SS / 2), dim3(128), 0, stream>>>(
        xyz, newxyz, ftr, idxbuf, cntbuf, W0p, b0, W1, b1, W2, b2, outfeat);
}

// Round 13
// 7436.958 us; speedup vs baseline: 2.1580x; 1.3242x over previous
//
#include <hip/hip_runtime.h>

#pragma clang fp contract(off)

#define BATCH 2
#define NPTS  16384
#define SS    4096
#define NSAMP 32
#define CIN   64

// ---------------------------------------------------------------------------
// prep: transpose features (B,64,N) -> (B,N,64); pack W0 (64x67) -> (64x68, 0-pad)
// ---------------------------------------------------------------------------
__global__ __launch_bounds__(256) void prep_kernel(
    const float* __restrict__ feat, const float* __restrict__ W0,
    float* __restrict__ ftr, float* __restrict__ W0p)
{
    __shared__ float tl[64][65];
    const int t = threadIdx.x;
    const int blk = blockIdx.x;
    if (blk < BATCH * (NPTS / 64)) {
        const int b  = blk / (NPTS / 64);
        const int n0 = (blk % (NPTS / 64)) * 64;
        #pragma unroll
        for (int k = 0; k < 16; ++k) {
            int c = k * 4 + (t >> 6);
            int n = t & 63;
            tl[c][n] = feat[((size_t)b * CIN + c) * NPTS + n0 + n];
        }
        __syncthreads();
        #pragma unroll
        for (int k = 0; k < 16; ++k) {
            int n = k * 4 + (t >> 6);
            int c = t & 63;
            ftr[((size_t)b * NPTS + n0 + n) * CIN + c] = tl[c][n];
        }
    } else {
        for (int i = t; i < 64 * 68; i += 256) {
            int r = i / 68, c = i % 68;
            W0p[i] = (c < 67) ? W0[r * 67 + c] : 0.f;
        }
    }
}

// ---------------------------------------------------------------------------
// u64-key DPP tournament hop: 2 v_mov_dpp + v_cmp_lt_u64 + 2 cndmask (~20cyc
// latency) vs ~130cyc for a ds_bpermute-based __shfl hop. Key packing
//   (float_bits(bv) << 32) | (0xFFFFFFFF - idx)
// is order-isomorphic to (bv desc-max, idx asc-min): bv >= 0 so float bits
// are monotone; tie in bv -> larger (0xFFFFFFFF-idx) -> smaller idx. This is
// numpy argmax first-occurrence exactly. Hop sequences are r10-proven
// (passed, absmax 0) -- only the payload width changes.
// ---------------------------------------------------------------------------
#define KHOP(CTRL, K)                                                         \
    {                                                                         \
        unsigned int _lo = (unsigned int)(K);                                 \
        unsigned int _hi = (unsigned int)((K) >> 32);                         \
        _lo = (unsigned int)__builtin_amdgcn_update_dpp(                      \
            (int)_lo, (int)_lo, CTRL, 0xF, 0xF, false);                       \
        _hi = (unsigned int)__builtin_amdgcn_update_dpp(                      \
            (int)_hi, (int)_hi, CTRL, 0xF, 0xF, false);                       \
        unsigned long long _ok = ((unsigned long long)_hi << 32) | _lo;       \
        K = _ok > K ? _ok : K;                                                \
    }
// dpp_ctrl: quad_perm[1,0,3,2]=0xB1, [2,3,0,1]=0x4E, row_half_mirror=0x141,
// row_mirror=0x140, row_bcast15=0x142 (lane15->row1, lane47->row3),
// row_bcast31=0x143 (lane31->rows2,3): lane 63 ends with the wave total.

// ---------------------------------------------------------------------------
// FPS v8: r9 structure (LDS xy, scalar update, max-tree+scan, scalar winner
// fetch) with BOTH shuffle chains replaced by u64-key DPP tournaments.
// r5-r12 ledger: coord path irrelevant (scratch/L2/LDS all ~2.15us); update
// VALU edits +-8%; the ~1300cyc of bpermute-chain latency is the remaining
// attackable term. Exact FP: contract off, ((dx2+dy2)+dz2), tie smallest idx.
// ---------------------------------------------------------------------------
__global__ __launch_bounds__(1024) void fps_kernel(
    const float* __restrict__ xyz, float* __restrict__ newxyz)
{
    #pragma clang fp contract(off)
    const int b = blockIdx.x;
    const int t = threadIdx.x;
    const float* xb = xyz + (size_t)b * NPTS * 3;

    __shared__ float2 sxy[NPTS];                 // 128 KB: (x,y) per point
    __shared__ unsigned long long s_k[2][16];    // per-wave winner key

    float pz[16], md[16];
    #pragma unroll
    for (int k = 0; k < 16; ++k) {
        int p = (k << 10) + t;
        float x = xb[p * 3 + 0];
        float y = xb[p * 3 + 1];
        float z = xb[p * 3 + 2];
        sxy[p] = make_float2(x, y);
        pz[k] = z;
        md[k] = 1e10f;
    }
    __syncthreads();

    const float2* sp0 = sxy + t;          // k = 0..7  : imm offset k*8192 B
    const float2* sp1 = sxy + t + 8192;   // k = 8..15 : imm offset (k-8)*8192 B

    float lx = xb[0], ly = xb[1], lz = xb[2];
    if (t == 0) {
        float* o = newxyz + (size_t)b * SS * 3;
        o[0] = lx; o[1] = ly; o[2] = lz;
    }

    for (int s = 1; s < SS; ++s) {
        // ---- min-update only (scalar r9 form; r12's packed asm regressed)
        #pragma unroll
        for (int k = 0; k < 8; ++k) {
            float2 xy = sp0[k << 10];
            float dx = xy.x - lx, dy = xy.y - ly, dz = pz[k] - lz;
            float d = (dx * dx + dy * dy) + dz * dz;   // contract(off): exact order
            md[k] = d < md[k] ? d : md[k];
        }
        #pragma unroll
        for (int k = 0; k < 8; ++k) {
            float2 xy = sp1[k << 10];
            float dx = xy.x - lx, dy = xy.y - ly, dz = pz[k + 8] - lz;
            float d = (dx * dx + dy * dy) + dz * dz;
            md[k + 8] = d < md[k + 8] ? d : md[k + 8];
        }

        // ---- bv = max over md (exact; max associative), v_max3-friendly tree
        float t0 = fmaxf(fmaxf(md[0],  md[1]),  md[2]);
        float t1 = fmaxf(fmaxf(md[3],  md[4]),  md[5]);
        float t2 = fmaxf(fmaxf(md[6],  md[7]),  md[8]);
        float t3 = fmaxf(fmaxf(md[9],  md[10]), md[11]);
        float t4 = fmaxf(fmaxf(md[12], md[13]), md[14]);
        float u0 = fmaxf(fmaxf(t0, t1), t2);
        float u1 = fmaxf(fmaxf(t3, t4), md[15]);
        float bv = fmaxf(u0, u1);

        // ---- bk = smallest k with md[k]==bv (reverse scan, inline-const k)
        int bk = 0;
        #pragma unroll
        for (int k = 15; k >= 0; --k)
            if (md[k] == bv) bk = k;
        int bi = (bk << 10) + t;

        // ---- wave tournament: 6 DPP hops on the packed key (lane 63 = total)
        unsigned long long key =
            ((unsigned long long)__float_as_uint(bv) << 32) |
            (unsigned long long)(0xFFFFFFFFu - (unsigned)bi);
        KHOP(0xB1,  key)
        KHOP(0x4E,  key)
        KHOP(0x141, key)
        KHOP(0x140, key)
        KHOP(0x142, key)
        KHOP(0x143, key)

        const int pb = s & 1;
        if ((t & 63) == 63)
            s_k[pb][t >> 6] = key;
        __syncthreads();

        // ---- 16-winner reduce: 4 DPP hops within each 16-lane row (every
        // row loads the same 16 entries -> every lane ends with the winner)
        unsigned long long rk = s_k[pb][t & 15];
        KHOP(0xB1,  rk)
        KHOP(0x4E,  rk)
        KHOP(0x141, rk)
        KHOP(0x140, rk)

        // winner coords from global (uniform address, L1/L2-resident)
        const int wi = (int)(0xFFFFFFFFu - (unsigned)rk);
        const int wu = __builtin_amdgcn_readfirstlane(wi);
        lx = xb[wu * 3 + 0];
        ly = xb[wu * 3 + 1];
        lz = xb[wu * 3 + 2];
        if (t == 0) {
            float* o = newxyz + ((size_t)b * SS + s) * 3;
            o[0] = lx; o[1] = ly; o[2] = lz;
        }
    }
}

// ---------------------------------------------------------------------------
// Ball query: one wave per query. First NSAMP valid indices in index order,
// pad with first valid, cnt flag. Exact FP compare semantics.
// ---------------------------------------------------------------------------
__global__ __launch_bounds__(256) void bq_kernel(
    const float* __restrict__ xyz, const float* __restrict__ newxyz,
    int* __restrict__ idxout, int* __restrict__ cntout)
{
    #pragma clang fp contract(off)
    const int lane = threadIdx.x & 63;
    const int q = blockIdx.x * 4 + (threadIdx.x >> 6);
    const int b = q >> 12;
    const float r2 = (float)(0.08 * 0.08);
    const float cx = newxyz[q * 3 + 0];
    const float cy = newxyz[q * 3 + 1];
    const float cz = newxyz[q * 3 + 2];
    const float* xb = xyz + (size_t)b * NPTS * 3;

    int found = 0;
    int idx0 = 0;
    for (int base = 0; base < NPTS; base += 64) {
        int p = base + lane;
        float dx = xb[p * 3 + 0] - cx;
        float dy = xb[p * 3 + 1] - cy;
        float dz = xb[p * 3 + 2] - cz;
        float d2 = (dx * dx + dy * dy) + dz * dz;   // contract(off)
        bool valid = d2 < r2;
        unsigned long long mask = __ballot(valid);
        if (mask) {
            if (found == 0) idx0 = base + (__ffsll(mask) - 1);
            int rank = found + __popcll(mask & ((1ull << lane) - 1ull));
            if (valid && rank < NSAMP) idxout[(size_t)q * NSAMP + rank] = p;
            found += (int)__popcll(mask);
            if (found >= NSAMP) break;
        }
    }
    if (found < NSAMP) {
        int pad = (found > 0) ? idx0 : 0;
        if (found + lane < NSAMP) idxout[(size_t)q * NSAMP + found + lane] = pad;
    }
    if (lane == 0) cntout[q] = found;
}

// ---------------------------------------------------------------------------
// Fused gather + 3-layer 1x1-conv MLP + masked max-pool.
// One wave per group; X/Y tiles in LDS (row stride 36 floats, conflict-free
// float4 access); weights streamed from global (L1-resident); explicit fmaf.
// ---------------------------------------------------------------------------
__global__ __launch_bounds__(128) void mlp_kernel(
    const float* __restrict__ xyz, const float* __restrict__ newxyz,
    const float* __restrict__ ftr, const int* __restrict__ idxbuf,
    const int* __restrict__ cntbuf, const float* __restrict__ W0p,
    const float* __restrict__ b0, const float* __restrict__ W1,
    const float* __restrict__ b1, const float* __restrict__ W2,
    const float* __restrict__ b2, float* __restrict__ outfeat)
{
    __shared__ float sX[2][68 * 36];
    __shared__ float sY[2][64 * 36];
    const int w    = threadIdx.x >> 6;
    const int lane = threadIdx.x & 63;
    const int g = blockIdx.x * 2 + w;
    const int b = g >> 12;
    const int s = g & (SS - 1);
    float* X = sX[w];
    float* Y = sY[w];

    const int n = lane & 31, h = lane >> 5;
    const int pidx = idxbuf[(size_t)g * NSAMP + n];
    const float cx = newxyz[g * 3 + 0];
    const float cy = newxyz[g * 3 + 1];
    const float cz = newxyz[g * 3 + 2];

    if (h == 0) {
        const float* p = xyz + ((size_t)b * NPTS + pidx) * 3;
        X[0 * 36 + n] = p[0] - cx;
        X[1 * 36 + n] = p[1] - cy;
        X[2 * 36 + n] = p[2] - cz;
        X[67 * 36 + n] = 0.f;
    }
    {
        const float4* f4 = (const float4*)(ftr + ((size_t)b * NPTS + pidx) * CIN + h * 32);
        #pragma unroll
        for (int j = 0; j < 8; ++j) {
            float4 v = f4[j];
            int c = 3 + h * 32 + j * 4;
            X[(c + 0) * 36 + n] = v.x;
            X[(c + 1) * 36 + n] = v.y;
            X[(c + 2) * 36 + n] = v.z;
            X[(c + 3) * 36 + n] = v.w;
        }
    }
    __syncthreads();

    const int og = lane >> 3, ng = lane & 7;

    // ---- Layer 0: 67(->68) -> 64
    float acc0[8][4];
    #pragma unroll
    for (int j = 0; j < 8; ++j)
        #pragma unroll
        for (int nn = 0; nn < 4; ++nn) acc0[j][nn] = 0.f;
    for (int cb = 0; cb < 17; ++cb) {
        const int c = cb * 4;
        float4 xr0 = *(const float4*)&X[(c + 0) * 36 + ng * 4];
        float4 xr1 = *(const float4*)&X[(c + 1) * 36 + ng * 4];
        float4 xr2 = *(const float4*)&X[(c + 2) * 36 + ng * 4];
        float4 xr3 = *(const float4*)&X[(c + 3) * 36 + ng * 4];
        #pragma unroll
        for (int j = 0; j < 8; ++j) {
            float4 wv = *(const float4*)&W0p[(size_t)(og * 8 + j) * 68 + c];
            acc0[j][0] = fmaf(wv.x, xr0.x, acc0[j][0]);
            acc0[j][1] = fmaf(wv.x, xr0.y, acc0[j][1]);
            acc0[j][2] = fmaf(wv.x, xr0.z, acc0[j][2]);
            acc0[j][3] = fmaf(wv.x, xr0.w, acc0[j][3]);
            acc0[j][0] = fmaf(wv.y, xr1.x, acc0[j][0]);
            acc0[j][1] = fmaf(wv.y, xr1.y, acc0[j][1]);
            acc0[j][2] = fmaf(wv.y, xr1.z, acc0[j][2]);
            acc0[j][3] = fmaf(wv.y, xr1.w, acc0[j][3]);
            acc0[j][0] = fmaf(wv.z, xr2.x, acc0[j][0]);
            acc0[j][1] = fmaf(wv.z, xr2.y, acc0[j][1]);
            acc0[j][2] = fmaf(wv.z, xr2.z, acc0[j][2]);
            acc0[j][3] = fmaf(wv.z, xr2.w, acc0[j][3]);
            acc0[j][0] = fmaf(wv.w, xr3.x, acc0[j][0]);
            acc0[j][1] = fmaf(wv.w, xr3.y, acc0[j][1]);
            acc0[j][2] = fmaf(wv.w, xr3.z, acc0[j][2]);
            acc0[j][3] = fmaf(wv.w, xr3.w, acc0[j][3]);
        }
    }
    #pragma unroll
    for (int j = 0; j < 8; ++j) {
        const float bv = b0[og * 8 + j];
        float4 yv;
        yv.x = fmaxf(acc0[j][0] + bv, 0.f);
        yv.y = fmaxf(acc0[j][1] + bv, 0.f);
        yv.z = fmaxf(acc0[j][2] + bv, 0.f);
        yv.w = fmaxf(acc0[j][3] + bv, 0.f);
        *(float4*)&Y[(og * 8 + j) * 36 + ng * 4] = yv;
    }
    __syncthreads();

    // ---- Layer 1: 64 -> 64  (Y -> X rows 0..63)
    float acc1[8][4];
    #pragma unroll
    for (int j = 0; j < 8; ++j)
        #pragma unroll
        for (int nn = 0; nn < 4; ++nn) acc1[j][nn] = 0.f;
    for (int cb = 0; cb < 16; ++cb) {
        const int c = cb * 4;
        float4 xr0 = *(const float4*)&Y[(c + 0) * 36 + ng * 4];
        float4 xr1 = *(const float4*)&Y[(c + 1) * 36 + ng * 4];
        float4 xr2 = *(const float4*)&Y[(c + 2) * 36 + ng * 4];
        float4 xr3 = *(const float4*)&Y[(c + 3) * 36 + ng * 4];
        #pragma unroll
        for (int j = 0; j < 8; ++j) {
            float4 wv = *(const float4*)&W1[(size_t)(og * 8 + j) * 64 + c];
            acc1[j][0] = fmaf(wv.x, xr0.x, acc1[j][0]);
            acc1[j][1] = fmaf(wv.x, xr0.y, acc1[j][1]);
            acc1[j][2] = fmaf(wv.x, xr0.z, acc1[j][2]);
            acc1[j][3] = fmaf(wv.x, xr0.w, acc1[j][3]);
            acc1[j][0] = fmaf(wv.y, xr1.x, acc1[j][0]);
            acc1[j][1] = fmaf(wv.y, xr1.y, acc1[j][1]);
            acc1[j][2] = fmaf(wv.y, xr1.z, acc1[j][2]);
            acc1[j][3] = fmaf(wv.y, xr1.w, acc1[j][3]);
            acc1[j][0] = fmaf(wv.z, xr2.x, acc1[j][0]);
            acc1[j][1] = fmaf(wv.z, xr2.y, acc1[j][1]);
            acc1[j][2] = fmaf(wv.z, xr2.z, acc1[j][2]);
            acc1[j][3] = fmaf(wv.z, xr2.w, acc1[j][3]);
            acc1[j][0] = fmaf(wv.w, xr3.x, acc1[j][0]);
            acc1[j][1] = fmaf(wv.w, xr3.y, acc1[j][1]);
            acc1[j][2] = fmaf(wv.w, xr3.z, acc1[j][2]);
            acc1[j][3] = fmaf(wv.w, xr3.w, acc1[j][3]);
        }
    }
    __syncthreads();   // X rows are about to be overwritten; Y reads done
    #pragma unroll
    for (int j = 0; j < 8; ++j) {
        const float bv = b1[og * 8 + j];
        float4 yv;
        yv.x = fmaxf(acc1[j][0] + bv, 0.f);
        yv.y = fmaxf(acc1[j][1] + bv, 0.f);
        yv.z = fmaxf(acc1[j][2] + bv, 0.f);
        yv.w = fmaxf(acc1[j][3] + bv, 0.f);
        *(float4*)&X[(og * 8 + j) * 36 + ng * 4] = yv;
    }
    __syncthreads();

    // ---- Layer 2: 64 -> 128 (X rows 0..63 -> registers) + masked max-pool
    float acc2[16][4];
    #pragma unroll
    for (int j = 0; j < 16; ++j)
        #pragma unroll
        for (int nn = 0; nn < 4; ++nn) acc2[j][nn] = 0.f;
    for (int cb = 0; cb < 16; ++cb) {
        const int c = cb * 4;
        float4 xr0 = *(const float4*)&X[(c + 0) * 36 + ng * 4];
        float4 xr1 = *(const float4*)&X[(c + 1) * 36 + ng * 4];
        float4 xr2 = *(const float4*)&X[(c + 2) * 36 + ng * 4];
        float4 xr3 = *(const float4*)&X[(c + 3) * 36 + ng * 4];
        #pragma unroll
        for (int j = 0; j < 16; ++j) {
            float4 wv = *(const float4*)&W2[(size_t)(og * 16 + j) * 64 + c];
            acc2[j][0] = fmaf(wv.x, xr0.x, acc2[j][0]);
            acc2[j][1] = fmaf(wv.x, xr0.y, acc2[j][1]);
            acc2[j][2] = fmaf(wv.x, xr0.z, acc2[j][2]);
            acc2[j][3] = fmaf(wv.x, xr0.w, acc2[j][3]);
            acc2[j][0] = fmaf(wv.y, xr1.x, acc2[j][0]);
            acc2[j][1] = fmaf(wv.y, xr1.y, acc2[j][1]);
            acc2[j][2] = fmaf(wv.y, xr1.z, acc2[j][2]);
            acc2[j][3] = fmaf(wv.y, xr1.w, acc2[j][3]);
            acc2[j][0] = fmaf(wv.z, xr2.x, acc2[j][0]);
            acc2[j][1] = fmaf(wv.z, xr2.y, acc2[j][1]);
            acc2[j][2] = fmaf(wv.z, xr2.z, acc2[j][2]);
            acc2[j][3] = fmaf(wv.z, xr2.w, acc2[j][3]);
            acc2[j][0] = fmaf(wv.w, xr3.x, acc2[j][0]);
            acc2[j][1] = fmaf(wv.w, xr3.y, acc2[j][1]);
            acc2[j][2] = fmaf(wv.w, xr3.z, acc2[j][2]);
            acc2[j][3] = fmaf(wv.w, xr3.w, acc2[j][3]);
        }
    }

    const int cnt = cntbuf[g];
    const float msk = (cnt > 0) ? 1.f : 0.f;
    float* ob = outfeat + ((size_t)b * 128) * SS + s;
    float mj[16];
    #pragma unroll
    for (int j = 0; j < 16; ++j) {
        const float bv = b2[og * 16 + j];
        float v0 = fmaxf(acc2[j][0] + bv, acc2[j][1] + bv);
        float v1 = fmaxf(acc2[j][2] + bv, acc2[j][3] + bv);
        float v = fmaxf(fmaxf(v0, v1), 0.f);
        v = fmaxf(v, __shfl_xor(v, 1));
        v = fmaxf(v, __shfl_xor(v, 2));
        v = fmaxf(v, __shfl_xor(v, 4));
        mj[j] = v * msk;
    }
    if (ng == 0) {
        #pragma unroll
        for (int j = 0; j < 16; ++j)
            ob[(size_t)(og * 16 + j) * SS] = mj[j];
    }
}

// ---------------------------------------------------------------------------
extern "C" void kernel_launch(void* const* d_in, const int* in_sizes, int n_in,
                              void* d_out, int out_size, void* d_ws, size_t ws_size,
                              hipStream_t stream)
{
    (void)in_sizes; (void)n_in; (void)out_size; (void)ws_size;
    const float* xyz  = (const float*)d_in[0];
    const float* feat = (const float*)d_in[1];
    const float* W0 = (const float*)d_in[2];
    const float* b0 = (const float*)d_in[3];
    const float* W1 = (const float*)d_in[4];
    const float* b1 = (const float*)d_in[5];
    const float* W2 = (const float*)d_in[6];
    const float* b2 = (const float*)d_in[7];

    float* out     = (float*)d_out;
    float* newxyz  = out;                          // (B,S,3)
    float* outfeat = out + (size_t)BATCH * SS * 3; // (B,128,S)

    char* ws = (char*)d_ws;
    float* ftr = (float*)ws;                                   // B*N*64 f32 (8 MB)
    size_t off = (size_t)BATCH * NPTS * CIN * sizeof(float);
    int* idxbuf = (int*)(ws + off); off += (size_t)BATCH * SS * NSAMP * sizeof(int);
    int* cntbuf = (int*)(ws + off); off += (size_t)BATCH * SS * sizeof(int);
    float* W0p  = (float*)(ws + off);

    prep_kernel<<<dim3(BATCH * (NPTS / 64) + 1), dim3(256), 0, stream>>>(feat, W0, ftr, W0p);
    fps_kernel<<<dim3(BATCH), dim3(1024), 0, stream>>>(xyz, newxyz);
    bq_kernel<<<dim3(BATCH * SS / 4), dim3(256), 0, stream>>>(xyz, newxyz, idxbuf, cntbuf);
    mlp_kernel<<<dim3(BATCH * SS / 2), dim3(128), 0, stream>>>(
        xyz, newxyz, ftr, idxbuf, cntbuf, W0p, b0, W1, b1, W2, b2, outfeat);
}